// Round 3
// baseline (540.366 us; speedup 1.0000x reference)
//
#include <hip/hip_runtime.h>

// SpatialTransformer: 3D trilinear warp, zeros padding.
// src [B,C,D,H,W] f32 = [2,2,128,160,128]; flow [B,3,D,H,W]; out [B,C,D,H,W].
//
// R11: SOFTWARE PIPELINE (y-march). R10 post-mortem: occupancy 52->73% but
// time flat ~70us -> wave count was NOT the limiter. New theory: phase
// convoy. All resident blocks run stage -> vmcnt(0)+barrier -> compute in
// lockstep, so HBM oscillates saturated/idle (avg 31%) while VALU idles
// during staging (38%). Latency-bound by STRUCTURE, not resources.
//  - Each block marches NY=10 y-tiles (a full 40-row y-group). Grid =
//    4 x 4 x 64 = 1024 blocks = exactly 4/CU, ONE dispatch round, no tail.
//  - Per step (T14 async-stage split): issue next tile's 8 src-chunk loads
//    + 3 flow loads into REGS before computing current tile from LDS;
//    after compute, barrier, ds_write regs->LDS, barrier. Loads get the
//    whole compute phase to land -> memory never idles, compute never
//    cold-waits.
//  - y-halo re-stage (6/10 rows) now hits this block's own L1.
//  - Single 31.25 KB buffer -> 4 blocks/CU; VGPR ~52 under (512,8)=64 cap
//    (R10 body was 20 -> no R5/R6 tight-cap spill risk).
// Fallback (outside halo window): ~0.5% of voxels, exact global gather x2ch.

#define B_ 2
#define C_ 2
#define D_ 128
#define H_ 160
#define W_ 128
constexpr int S_ = D_ * H_ * W_;

#define ZT 4
#define YT 4
#define XT 32
#define RZ 3
#define RY 3
#define RX 4
#define CZ (ZT + 2 * RZ)   // 10
#define CY (YT + 2 * RY)   // 10
#define CX (XT + 2 * RX)   // 40
#define NTHREADS 512
#define NCHUNK (CZ * CY * (CX / 2))    // 2000 16B chunks (x-pair x {c0,c1})
#define NY 10                          // y-tiles marched per block
#define YSTEP (YT * W_)                // flat-index advance per y-step (512)

__device__ __forceinline__ float pair_val(const float* p, bool hi0, bool lo1,
                                          float wx0, float wx1) {
    const float v0 = hi0 ? p[1] : p[0];
    const float v1 = lo1 ? p[0] : p[1];
    return wx0 * v0 + wx1 * v1;
}

// Read both channels at x-corners (xp, xp+1) from the interleaved tile and
// x-blend. o = float index of [z][y][xp][c0]. Returns {ch0, ch1}.
__device__ __forceinline__ float2 lds_pair2(const float* t, int o,
                                            bool hi0, bool lo1,
                                            float wx0, float wx1) {
    const float2 a = *(const float2*)&t[o];       // {c0(xp),   c1(xp)}
    const float2 b = *(const float2*)&t[o + 2];   // {c0(xp+1), c1(xp+1)}
    const float v00 = hi0 ? b.x : a.x;            // ch0 value at x0
    const float v01 = lo1 ? a.x : b.x;            // ch0 value at x0+1
    const float v10 = hi0 ? b.y : a.y;            // ch1
    const float v11 = lo1 ? a.y : b.y;
    return make_float2(wx0 * v00 + wx1 * v01, wx0 * v10 + wx1 * v11);
}

__global__ __launch_bounds__(NTHREADS, 8) void warp3d_tile(
    const float* __restrict__ src,
    const float* __restrict__ flow,
    float* __restrict__ out)
{
    __shared__ float tile[CZ * CY * CX * 2];   // 8000 floats = 31.25 KB

    const int tid = threadIdx.x;
    const int xb  = blockIdx.x * XT;
    const int yb0 = blockIdx.y * (YT * NY);
    const int bz  = blockIdx.z;
    const int zb  = (bz & 31) * ZT;        // 32 z-tiles
    const int b   = bz >> 5;               // batch

    const float* fb = flow + (long long)b * 3 * S_;
    const float* s0 = src + (long long)b * C_ * S_;   // ch0; ch1 = s0 + S_
    float* o0       = out + (long long)b * C_ * S_;   // ch0; ch1 = o0 + S_

    // ---- constant per-thread staging geometry (chunk j = j*512+tid) ----
    int offj[4];          // flat src index of this chunk (advances per step)
    int gyj[4];           // global y of this chunk (advances per step)
    bool vzx[4];          // z/x validity (+ lin<NCHUNK), loop-invariant
#pragma unroll
    for (int j = 0; j < 4; ++j) {
        const int lin = j * NTHREADS + tid;
        const int row = lin / 20;              // rz*CY+ry
        const int c   = lin - row * 20;        // x-pair 0..19
        const int rz = row / CY, ry = row - rz * CY;
        const int gz = zb - RZ + rz;
        const int gx = xb - RX + c * 2;
        gyj[j]  = yb0 - RY + ry;
        vzx[j]  = (lin < NCHUNK) && ((unsigned)gz < (unsigned)D_) &&
                  ((unsigned)gx <= (unsigned)(W_ - 2));
        offj[j] = (gz * H_ + gyj[j]) * W_ + gx;
    }

    // ---- this thread's voxel-pair column (y advances per step) ----
    const int lx = tid & 31, ly = (tid >> 5) & 3, lz = tid >> 7;
    const int x = xb + lx, z = zb + lz;
    int y_c = yb0 + ly;
    int s_c = (z * H_ + y_c) * W_ + x;

    // z/x fast-path bounds are loop-invariant
    const int zlo = max(0, zb - RZ), zhi = min(D_, zb + ZT + RZ);
    const int xlo = max(0, xb - RX), xhi = min(W_, xb + RX + XT);

    // ================= prologue: stage step 0 =================
    float fzc = fb[s_c], fyc = fb[S_ + s_c], fxc = fb[2 * S_ + s_c];
#pragma unroll
    for (int j = 0; j < 4; ++j) {
        if (vzx[j] && (unsigned)gyj[j] < (unsigned)H_) {
            const float2 a  = *(const float2*)(s0 + offj[j]);
            const float2 c2 = *(const float2*)(s0 + S_ + offj[j]);
            *(float4*)&tile[tid * 4 + j * 2048] = make_float4(a.x, c2.x, a.y, c2.y);
        }
        offj[j] += YSTEP; gyj[j] += YT;
    }
    __syncthreads();

    // ================= main pipeline =================
#pragma unroll 1
    for (int t = 0; t < NY; ++t) {
        const bool more = (t + 1 < NY);
        float4 pn[4];
        bool vld[4];
        float fzn, fyn, fxn;

        // ---- A) prefetch next step into regs (issued before compute) ----
        if (more) {
            const int sn = s_c + YSTEP;
            fzn = fb[sn]; fyn = fb[S_ + sn]; fxn = fb[2 * S_ + sn];
#pragma unroll
            for (int j = 0; j < 4; ++j) {
                vld[j] = vzx[j] && ((unsigned)gyj[j] < (unsigned)H_);
                if (vld[j]) {
                    const float2 a  = *(const float2*)(s0 + offj[j]);
                    const float2 c2 = *(const float2*)(s0 + S_ + offj[j]);
                    pn[j] = make_float4(a.x, c2.x, a.y, c2.y);
                }
                offj[j] += YSTEP; gyj[j] += YT;
            }
        }

        // ---- B) compute current step from LDS ----
        const int yb_c = yb0 + t * YT;
        const int ylo = max(0, yb_c - RY), yhi = min(H_, yb_c + YT + RY);

        const float iz = (float)z + fzc;
        const float iy = (float)y_c + fyc;
        const float ix = (float)x + fxc;

        const float zf = floorf(iz), yf = floorf(iy), xf = floorf(ix);
        const float tz = iz - zf, ty = iy - yf, tx = ix - xf;
        const int z0 = (int)zf, y0 = (int)yf, x0 = (int)xf;

        const int zc0 = min(max(z0, 0), D_ - 1), zc1 = min(max(z0 + 1, 0), D_ - 1);
        const int yc0 = min(max(y0, 0), H_ - 1), yc1 = min(max(y0 + 1, 0), H_ - 1);
        const int xp  = min(max(x0, 0), W_ - 2);

        const float wz0 = ((unsigned)z0       < (unsigned)D_) ? (1.f - tz) : 0.f;
        const float wz1 = ((unsigned)(z0 + 1) < (unsigned)D_) ? tz         : 0.f;
        const float wy0 = ((unsigned)y0       < (unsigned)H_) ? (1.f - ty) : 0.f;
        const float wy1 = ((unsigned)(y0 + 1) < (unsigned)H_) ? ty         : 0.f;
        const float wx0 = ((unsigned)x0       < (unsigned)W_) ? (1.f - tx) : 0.f;
        const float wx1 = ((unsigned)(x0 + 1) < (unsigned)W_) ? tx         : 0.f;
        const bool hi0 = x0 > xp;   // x0 == W-1
        const bool lo1 = x0 < xp;   // x0 == -1

        const bool fast = (zc0 >= zlo) & (zc1 < zhi) &
                          (yc0 >= ylo) & (yc1 < yhi) &
                          (xp >= xlo) & (xp + 1 < xhi);

        float acc0, acc1;
        if (fast) {
            const int izl0 = zc0 - (zb - RZ), izl1 = zc1 - (zb - RZ);
            const int iyl0 = yc0 - (yb_c - RY), iyl1 = yc1 - (yb_c - RY);
            const int ixl  = xp - (xb - RX);
            const int o00 = ((izl0 * CY + iyl0) * CX + ixl) * 2;
            const int o01 = ((izl0 * CY + iyl1) * CX + ixl) * 2;
            const int o10 = ((izl1 * CY + iyl0) * CX + ixl) * 2;
            const int o11 = ((izl1 * CY + iyl1) * CX + ixl) * 2;
            const float2 p00 = lds_pair2(tile, o00, hi0, lo1, wx0, wx1);
            const float2 p01 = lds_pair2(tile, o01, hi0, lo1, wx0, wx1);
            const float2 p10 = lds_pair2(tile, o10, hi0, lo1, wx0, wx1);
            const float2 p11 = lds_pair2(tile, o11, hi0, lo1, wx0, wx1);
            acc0 = wz0 * (wy0 * p00.x + wy1 * p01.x) + wz1 * (wy0 * p10.x + wy1 * p11.x);
            acc1 = wz0 * (wy0 * p00.y + wy1 * p01.y) + wz1 * (wy0 * p10.y + wy1 * p11.y);
        } else {
            const int l00 = (zc0 * H_ + yc0) * W_ + xp;
            const int l01 = (zc0 * H_ + yc1) * W_ + xp;
            const int l10 = (zc1 * H_ + yc0) * W_ + xp;
            const int l11 = (zc1 * H_ + yc1) * W_ + xp;
            const float q00 = pair_val(s0 + l00, hi0, lo1, wx0, wx1);
            const float q01 = pair_val(s0 + l01, hi0, lo1, wx0, wx1);
            const float q10 = pair_val(s0 + l10, hi0, lo1, wx0, wx1);
            const float q11 = pair_val(s0 + l11, hi0, lo1, wx0, wx1);
            const float r00 = pair_val(s0 + S_ + l00, hi0, lo1, wx0, wx1);
            const float r01 = pair_val(s0 + S_ + l01, hi0, lo1, wx0, wx1);
            const float r10 = pair_val(s0 + S_ + l10, hi0, lo1, wx0, wx1);
            const float r11 = pair_val(s0 + S_ + l11, hi0, lo1, wx0, wx1);
            acc0 = wz0 * (wy0 * q00 + wy1 * q01) + wz1 * (wy0 * q10 + wy1 * q11);
            acc1 = wz0 * (wy0 * r00 + wy1 * r01) + wz1 * (wy0 * r10 + wy1 * r11);
        }
        o0[s_c]      = acc0;
        o0[S_ + s_c] = acc1;

        __syncthreads();   // everyone done reading tile for step t

        // ---- C) write prefetched regs -> LDS, roll state ----
        if (more) {
#pragma unroll
            for (int j = 0; j < 4; ++j)
                if (vld[j]) *(float4*)&tile[tid * 4 + j * 2048] = pn[j];
            fzc = fzn; fyc = fyn; fxc = fxn;
            s_c += YSTEP; y_c += YT;
        }
        __syncthreads();   // tile for step t+1 ready
    }
}

extern "C" void kernel_launch(void* const* d_in, const int* in_sizes, int n_in,
                              void* d_out, int out_size, void* d_ws, size_t ws_size,
                              hipStream_t stream) {
    const float* src  = (const float*)d_in[0];
    const float* flow = (const float*)d_in[1];
    float* out = (float*)d_out;

    // grid: x 4, y 4 (y-groups of 40 rows), z = 32 z-tiles x B2 = 64
    //  -> 1024 blocks = exactly 4 per CU, one dispatch round, no tail.
    dim3 grid(W_ / XT, H_ / (YT * NY), (D_ / ZT) * B_);
    warp3d_tile<<<grid, NTHREADS, 0, stream>>>(src, flow, out);
}

// Round 4
// 180.797 us; speedup vs baseline: 2.9888x; 2.9888x over previous
//
#include <hip/hip_runtime.h>

// SpatialTransformer: 3D trilinear warp, zeros padding.
// src [B,C,D,H,W] f32 = [2,2,128,160,128]; flow [B,3,D,H,W]; out [B,C,D,H,W].
//
// R12: R11's pipeline, SPILL-PROOFED. R11 post-mortem: WRITE 41->900 MB,
// FETCH 133->910 MB (symmetric = scratch), VALU 7% -> the conditionally-
// written prefetch arrays (pn[4]/vld[4]) living across __syncthreads under
// a 64-VGPR cap were demoted to scratch (rule-#20 pattern). The convoy
// theory was never tested. Fixes:
//  - ZERO conditionals in staging: all addresses pre-clamped in-bounds
//    (gz/gx clamped once, gy clamped per step). Out-of-range halo cells
//    hold garbage that the fast path never reads (its corner window is
//    clamped to the valid global range). Phantom chunks (lin>=2000) land
//    in a padded 8192-float tile (32 KB -> still 5 blocks/CU by LDS).
//  - Prefetch in NAMED scalars p0..p3, loaded + written UNconditionally
//    every step (last-step write is dead data, never read).
//  - launch_bounds(512,4): 128-VGPR cap, body ~70 -> allocator slack.
// Structure kept from R11: each block marches NY=10 y-tiles; grid 4x4x64 =
// 1024 blocks = exactly 4/CU, one dispatch round; per step issue next
// tile's 8 global loads + 3 flow loads BEFORE computing current tile from
// LDS (T14 issue-early/write-late) so HBM latency hides under compute.
// Fallback (outside halo window): ~0.5% of voxels, exact global gather x2ch.

#define B_ 2
#define C_ 2
#define D_ 128
#define H_ 160
#define W_ 128
constexpr int S_ = D_ * H_ * W_;

#define ZT 4
#define YT 4
#define XT 32
#define RZ 3
#define RY 3
#define RX 4
#define CZ (ZT + 2 * RZ)   // 10
#define CY (YT + 2 * RY)   // 10
#define CX (XT + 2 * RX)   // 40
#define NTHREADS 512
#define NCHUNK (CZ * CY * (CX / 2))    // 2000 real 16B chunks
#define NY 10                          // y-tiles marched per block
#define YSTEP (YT * W_)                // flat-index advance per y-step

__device__ __forceinline__ float pair_val(const float* p, bool hi0, bool lo1,
                                          float wx0, float wx1) {
    const float v0 = hi0 ? p[1] : p[0];
    const float v1 = lo1 ? p[0] : p[1];
    return wx0 * v0 + wx1 * v1;
}

// Read both channels at x-corners (xp, xp+1) from the interleaved tile and
// x-blend. o = float index of [z][y][xp][c0]. Returns {ch0, ch1}.
__device__ __forceinline__ float2 lds_pair2(const float* t, int o,
                                            bool hi0, bool lo1,
                                            float wx0, float wx1) {
    const float2 a = *(const float2*)&t[o];       // {c0(xp),   c1(xp)}
    const float2 b = *(const float2*)&t[o + 2];   // {c0(xp+1), c1(xp+1)}
    const float v00 = hi0 ? b.x : a.x;            // ch0 value at x0
    const float v01 = lo1 ? a.x : b.x;            // ch0 value at x0+1
    const float v10 = hi0 ? b.y : a.y;            // ch1
    const float v11 = lo1 ? a.y : b.y;
    return make_float2(wx0 * v00 + wx1 * v01, wx0 * v10 + wx1 * v11);
}

// Load one interleaved 16B chunk (x-pair x {c0,c1}) from clamped address.
#define CHUNK_LOAD(J, P)                                                    \
    {                                                                       \
        const int gyc = min(max(gyj##J, 0), H_ - 1);                        \
        const int off = base##J + gyc * W_;                                 \
        const float2 a  = *(const float2*)(s0 + off);                       \
        const float2 cc = *(const float2*)(s0 + S_ + off);                  \
        P = make_float4(a.x, cc.x, a.y, cc.y);                              \
        gyj##J += YT;                                                       \
    }

// Per-chunk invariant geometry for chunk lin = J*512+tid (clamped in-bounds).
#define CHUNK_GEOM(J)                                                       \
    int base##J, gyj##J;                                                    \
    {                                                                       \
        const int lin = J * NTHREADS + tid;                                 \
        const int row = lin / 20;                                           \
        const int c   = lin - row * 20;                                     \
        const int rz  = row / CY, ry = row - rz * CY;                       \
        const int gz  = min(max(zb - RZ + rz, 0), D_ - 1);                  \
        const int gx  = min(max(xb - RX + c * 2, 0), W_ - 2);               \
        gyj##J  = yb0 - RY + ry;                                            \
        base##J = gz * (H_ * W_) + gx;                                      \
    }

__global__ __launch_bounds__(NTHREADS, 4) void warp3d_tile(
    const float* __restrict__ src,
    const float* __restrict__ flow,
    float* __restrict__ out)
{
    __shared__ float tile[8192];   // 2000 real + 48 phantom chunks = 32 KB

    const int tid = threadIdx.x;
    const int xb  = blockIdx.x * XT;
    const int yb0 = blockIdx.y * (YT * NY);
    const int bz  = blockIdx.z;
    const int zb  = (bz & 31) * ZT;        // 32 z-tiles
    const int b   = bz >> 5;               // batch

    const float* fb = flow + (long long)b * 3 * S_;
    const float* s0 = src + (long long)b * C_ * S_;   // ch0; ch1 = s0 + S_
    float* o0       = out + (long long)b * C_ * S_;   // ch0; ch1 = o0 + S_

    CHUNK_GEOM(0) CHUNK_GEOM(1) CHUNK_GEOM(2) CHUNK_GEOM(3)

    // ---- this thread's voxel-pair column (y advances per step) ----
    const int lx = tid & 31, ly = (tid >> 5) & 3, lz = tid >> 7;
    const int x = xb + lx, z = zb + lz;
    int y_c = yb0 + ly;
    int s_c = (z * H_ + y_c) * W_ + x;

    // z/x fast-path bounds are loop-invariant
    const int zlo = max(0, zb - RZ), zhi = min(D_, zb + ZT + RZ);
    const int xlo = max(0, xb - RX), xhi = min(W_, xb + RX + XT);

    // ================= prologue: stage step 0 =================
    float fzc = fb[s_c], fyc = fb[S_ + s_c], fxc = fb[2 * S_ + s_c];
    {
        float4 p0, p1, p2, p3;
        CHUNK_LOAD(0, p0) CHUNK_LOAD(1, p1) CHUNK_LOAD(2, p2) CHUNK_LOAD(3, p3)
        *(float4*)&tile[tid * 4]        = p0;
        *(float4*)&tile[tid * 4 + 2048] = p1;
        *(float4*)&tile[tid * 4 + 4096] = p2;
        *(float4*)&tile[tid * 4 + 6144] = p3;
    }
    __syncthreads();

    // ================= main pipeline =================
#pragma unroll 1
    for (int t = 0; t < NY; ++t) {
        // ---- A) prefetch next step into registers (clamped, unconditional)
        const int yn = min(y_c + YT, H_ - 1);
        const int sn = (z * H_ + yn) * W_ + x;
        const float fzn = fb[sn], fyn = fb[S_ + sn], fxn = fb[2 * S_ + sn];
        float4 p0, p1, p2, p3;
        CHUNK_LOAD(0, p0) CHUNK_LOAD(1, p1) CHUNK_LOAD(2, p2) CHUNK_LOAD(3, p3)

        // ---- B) compute current step from LDS ----
        const int yb_c = yb0 + t * YT;
        const int ylo = max(0, yb_c - RY), yhi = min(H_, yb_c + YT + RY);

        const float iz = (float)z + fzc;
        const float iy = (float)y_c + fyc;
        const float ix = (float)x + fxc;

        const float zf = floorf(iz), yf = floorf(iy), xf = floorf(ix);
        const float tz = iz - zf, ty = iy - yf, tx = ix - xf;
        const int z0 = (int)zf, y0 = (int)yf, x0 = (int)xf;

        const int zc0 = min(max(z0, 0), D_ - 1), zc1 = min(max(z0 + 1, 0), D_ - 1);
        const int yc0 = min(max(y0, 0), H_ - 1), yc1 = min(max(y0 + 1, 0), H_ - 1);
        const int xp  = min(max(x0, 0), W_ - 2);

        const float wz0 = ((unsigned)z0       < (unsigned)D_) ? (1.f - tz) : 0.f;
        const float wz1 = ((unsigned)(z0 + 1) < (unsigned)D_) ? tz         : 0.f;
        const float wy0 = ((unsigned)y0       < (unsigned)H_) ? (1.f - ty) : 0.f;
        const float wy1 = ((unsigned)(y0 + 1) < (unsigned)H_) ? ty         : 0.f;
        const float wx0 = ((unsigned)x0       < (unsigned)W_) ? (1.f - tx) : 0.f;
        const float wx1 = ((unsigned)(x0 + 1) < (unsigned)W_) ? tx         : 0.f;
        const bool hi0 = x0 > xp;   // x0 == W-1
        const bool lo1 = x0 < xp;   // x0 == -1

        const bool fast = (zc0 >= zlo) & (zc1 < zhi) &
                          (yc0 >= ylo) & (yc1 < yhi) &
                          (xp >= xlo) & (xp + 1 < xhi);

        float acc0, acc1;
        if (fast) {
            const int izl0 = zc0 - (zb - RZ), izl1 = zc1 - (zb - RZ);
            const int iyl0 = yc0 - (yb_c - RY), iyl1 = yc1 - (yb_c - RY);
            const int ixl  = xp - (xb - RX);
            const int o00 = ((izl0 * CY + iyl0) * CX + ixl) * 2;
            const int o01 = ((izl0 * CY + iyl1) * CX + ixl) * 2;
            const int o10 = ((izl1 * CY + iyl0) * CX + ixl) * 2;
            const int o11 = ((izl1 * CY + iyl1) * CX + ixl) * 2;
            const float2 p00 = lds_pair2(tile, o00, hi0, lo1, wx0, wx1);
            const float2 p01 = lds_pair2(tile, o01, hi0, lo1, wx0, wx1);
            const float2 p10 = lds_pair2(tile, o10, hi0, lo1, wx0, wx1);
            const float2 p11 = lds_pair2(tile, o11, hi0, lo1, wx0, wx1);
            acc0 = wz0 * (wy0 * p00.x + wy1 * p01.x) + wz1 * (wy0 * p10.x + wy1 * p11.x);
            acc1 = wz0 * (wy0 * p00.y + wy1 * p01.y) + wz1 * (wy0 * p10.y + wy1 * p11.y);
        } else {
            const int l00 = (zc0 * H_ + yc0) * W_ + xp;
            const int l01 = (zc0 * H_ + yc1) * W_ + xp;
            const int l10 = (zc1 * H_ + yc0) * W_ + xp;
            const int l11 = (zc1 * H_ + yc1) * W_ + xp;
            const float q00 = pair_val(s0 + l00, hi0, lo1, wx0, wx1);
            const float q01 = pair_val(s0 + l01, hi0, lo1, wx0, wx1);
            const float q10 = pair_val(s0 + l10, hi0, lo1, wx0, wx1);
            const float q11 = pair_val(s0 + l11, hi0, lo1, wx0, wx1);
            const float r00 = pair_val(s0 + S_ + l00, hi0, lo1, wx0, wx1);
            const float r01 = pair_val(s0 + S_ + l01, hi0, lo1, wx0, wx1);
            const float r10 = pair_val(s0 + S_ + l10, hi0, lo1, wx0, wx1);
            const float r11 = pair_val(s0 + S_ + l11, hi0, lo1, wx0, wx1);
            acc0 = wz0 * (wy0 * q00 + wy1 * q01) + wz1 * (wy0 * q10 + wy1 * q11);
            acc1 = wz0 * (wy0 * r00 + wy1 * r01) + wz1 * (wy0 * r10 + wy1 * r11);
        }
        o0[s_c]      = acc0;
        o0[S_ + s_c] = acc1;

        __syncthreads();   // everyone done reading tile for step t

        // ---- C) write prefetched regs -> LDS (unconditional), roll state
        *(float4*)&tile[tid * 4]        = p0;
        *(float4*)&tile[tid * 4 + 2048] = p1;
        *(float4*)&tile[tid * 4 + 4096] = p2;
        *(float4*)&tile[tid * 4 + 6144] = p3;
        fzc = fzn; fyc = fyn; fxc = fxn;
        s_c += YSTEP; y_c += YT;
        __syncthreads();   // tile for step t+1 ready
    }
}

extern "C" void kernel_launch(void* const* d_in, const int* in_sizes, int n_in,
                              void* d_out, int out_size, void* d_ws, size_t ws_size,
                              hipStream_t stream) {
    const float* src  = (const float*)d_in[0];
    const float* flow = (const float*)d_in[1];
    float* out = (float*)d_out;

    // grid: x 4, y 4 (y-groups of 40 rows), z = 32 z-tiles x B2 = 64
    //  -> 1024 blocks = exactly 4 per CU, one dispatch round, no tail.
    dim3 grid(W_ / XT, H_ / (YT * NY), (D_ / ZT) * B_);
    warp3d_tile<<<grid, NTHREADS, 0, stream>>>(src, flow, out);
}